// Round 1
// baseline (290.876 us; speedup 1.0000x reference)
//
#include <hip/hip_runtime.h>
#include <hip/hip_bf16.h>

#define GAT_ALPHA 0.2f
#define LOG2E 1.4426950408889634f

typedef float f32x4 __attribute__((ext_vector_type(4)));
typedef int   i32x4 __attribute__((ext_vector_type(4)));
typedef short bf16x8 __attribute__((ext_vector_type(8)));

static constexpr int Bn  = 8;
static constexpr int Nn  = 2048;
static constexpr int FIN = 256;
static constexpr int FO  = 128;

static __device__ __forceinline__ unsigned short f2bf(float x) {
    __hip_bfloat16 h = __float2bfloat16(x);
    return __builtin_bit_cast(unsigned short, h);
}
static __device__ __forceinline__ float bf2f(unsigned short u) {
    unsigned int v = ((unsigned int)u) << 16;
    return __builtin_bit_cast(float, v);
}

// Kernel 1: Wh = h@W (fp32), store WhT bf16 [b][f][n] (transposed for MFMA B-frags),
// s_src = Wh@a[:128], s_dst = Wh@a[128:] in fp32.
__global__ __launch_bounds__(256) void gat_wh(
        const float* __restrict__ h, const float* __restrict__ W,
        const float* __restrict__ a, unsigned short* __restrict__ WhT,
        float* __restrict__ s_src, float* __restrict__ s_dst)
{
    __shared__ float hs[32][256];   // 32 KB
    __shared__ float ssl[32];
    __shared__ float sdl[32];
    const int t  = threadIdx.x;
    const int b  = blockIdx.x & 7;           // XCD-friendly: batch per XCD
    const int n0 = (blockIdx.x >> 3) << 5;   // 64 row-tiles of 32
    if (t < 32) { ssl[t] = 0.f; sdl[t] = 0.f; }
    const float* hb = h + ((size_t)(b * Nn + n0)) * FIN;
    #pragma unroll
    for (int c = 0; c < 8; ++c) {
        int idx = c * 256 + t;
        int row = idx >> 6;
        int kk  = (idx & 63) << 2;
        *(f32x4*)&hs[row][kk] = *(const f32x4*)&hb[(size_t)row * FIN + kk];
    }
    __syncthreads();
    const int r0 = (t >> 5) << 2;     // row base 0..28
    const int fb = (t & 31) << 2;     // feature base 0..124
    float acc[4][4] = {};
    for (int k = 0; k < FIN; k += 4) {
        f32x4 hv[4];
        #pragma unroll
        for (int i = 0; i < 4; ++i) hv[i] = *(const f32x4*)&hs[r0 + i][k];
        #pragma unroll
        for (int kk = 0; kk < 4; ++kk) {
            f32x4 wv = *(const f32x4*)&W[(size_t)(k + kk) * FO + fb];
            #pragma unroll
            for (int i = 0; i < 4; ++i) {
                acc[i][0] += hv[i][kk] * wv[0];
                acc[i][1] += hv[i][kk] * wv[1];
                acc[i][2] += hv[i][kk] * wv[2];
                acc[i][3] += hv[i][kk] * wv[3];
            }
        }
    }
    // transposed bf16 store: WhT[b][f][n]
    #pragma unroll
    for (int j = 0; j < 4; ++j) {
        ushort4 pk;
        pk.x = f2bf(acc[0][j]); pk.y = f2bf(acc[1][j]);
        pk.z = f2bf(acc[2][j]); pk.w = f2bf(acc[3][j]);
        *(ushort4*)&WhT[(size_t)(b * FO + fb + j) * Nn + n0 + r0] = pk;
    }
    // s_src / s_dst partials (fp32, from fp32 Wh)
    f32x4 as = *(const f32x4*)&a[fb];
    f32x4 ad = *(const f32x4*)&a[FO + fb];
    #pragma unroll
    for (int i = 0; i < 4; ++i) {
        float ps = acc[i][0]*as[0] + acc[i][1]*as[1] + acc[i][2]*as[2] + acc[i][3]*as[3];
        float pd = acc[i][0]*ad[0] + acc[i][1]*ad[1] + acc[i][2]*ad[2] + acc[i][3]*ad[3];
        atomicAdd(&ssl[r0 + i], ps);
        atomicAdd(&sdl[r0 + i], pd);
    }
    __syncthreads();
    if (t < 32) {
        s_src[b * Nn + n0 + t] = ssl[t];
        s_dst[b * Nn + n0 + t] = sdl[t];
    }
}

// Kernel 2: md[b] = max_n s_dst[b][n]  (for softmax overflow guard; any per-row
// upper bound works since lrelu is monotone: m_i = lrelu(s_src_i + md_b) >= e_ij)
__global__ __launch_bounds__(256) void gat_max(
        const float* __restrict__ s_dst, float* __restrict__ md)
{
    __shared__ float red[256];
    const int t = threadIdx.x;
    const int b = blockIdx.x;
    float m = -3.4e38f;
    for (int i = t; i < Nn; i += 256) m = fmaxf(m, s_dst[b * Nn + i]);
    red[t] = m;
    __syncthreads();
    for (int s = 128; s > 0; s >>= 1) {
        if (t < s) red[t] = fmaxf(red[t], red[t + s]);
        __syncthreads();
    }
    if (t == 0) md[b] = red[0];
}

// Kernel 3: per block: 32 i-rows, full 128 features. 4 waves k-split over j.
// A-fragment (P tile) computed in registers straight from global adj reads;
// B-fragments from pre-transposed WhT. No barriers in main loop.
__global__ __launch_bounds__(256, 2) void gat_attn(
        const int* __restrict__ adj, const unsigned short* __restrict__ WhT,
        const float* __restrict__ s_src, const float* __restrict__ s_dst,
        const float* __restrict__ md, float* __restrict__ out)
{
    __shared__ float accbuf[2][32][FO];   // 32 KB cross-wave reduction
    __shared__ float l_red[32];
    const int t    = threadIdx.x;
    const int w    = t >> 6;
    const int lane = t & 63;
    const int n16  = lane & 15;
    const int quad = lane >> 4;
    const int b  = blockIdx.x & 7;           // batch per XCD for WhT L2 locality
    const int i0 = (blockIdx.x >> 3) << 5;

    const float mdb = md[b];
    const float ss0 = s_src[b * Nn + i0 + n16];
    const float ss1 = s_src[b * Nn + i0 + 16 + n16];
    const float mi0 = fmaxf(ss0 + mdb, GAT_ALPHA * (ss0 + mdb)) * LOG2E;
    const float mi1 = fmaxf(ss1 + mdb, GAT_ALPHA * (ss1 + mdb)) * LOG2E;

    const int* adj0 = adj + ((size_t)(b * Nn + i0 + n16)) * Nn + (quad << 3);
    const int* adj1 = adj0 + (size_t)16 * Nn;
    const float* dp = s_dst + b * Nn + (quad << 3);
    const unsigned short* whp = WhT + ((size_t)(b * FO + n16)) * Nn + (quad << 3);

    f32x4 acc[2][8] = {};
    float ls0 = 0.f, ls1 = 0.f;

    for (int s = 0; s < Nn; s += 128) {
        const int j0 = s + (w << 5);   // wave k-split: wave w owns k = j0..j0+31
        i32x4 a00 = *(const i32x4*)(adj0 + j0);
        i32x4 a01 = *(const i32x4*)(adj0 + j0 + 4);
        i32x4 a10 = *(const i32x4*)(adj1 + j0);
        i32x4 a11 = *(const i32x4*)(adj1 + j0 + 4);
        f32x4 d0v = *(const f32x4*)(dp + j0);
        f32x4 d1v = *(const f32x4*)(dp + j0 + 4);
        float dv[8]  = {d0v[0], d0v[1], d0v[2], d0v[3], d1v[0], d1v[1], d1v[2], d1v[3]};
        int   am0[8] = {a00[0], a00[1], a00[2], a00[3], a01[0], a01[1], a01[2], a01[3]};
        int   am1[8] = {a10[0], a10[1], a10[2], a10[3], a11[0], a11[1], a11[2], a11[3]};
        bf16x8 af0, af1;
        #pragma unroll
        for (int j = 0; j < 8; ++j) {
            float t0 = ss0 + dv[j];
            float t1 = ss1 + dv[j];
            float e0 = __builtin_amdgcn_exp2f(__builtin_fmaf(fmaxf(t0, GAT_ALPHA * t0), LOG2E, -mi0));
            float e1 = __builtin_amdgcn_exp2f(__builtin_fmaf(fmaxf(t1, GAT_ALPHA * t1), LOG2E, -mi1));
            e0 = (am0[j] > 0) ? e0 : 0.f;   // mask: matches exp(NEG_INF - m) -> 0
            e1 = (am1[j] > 0) ? e1 : 0.f;
            unsigned short u0 = f2bf(e0);
            unsigned short u1 = f2bf(e1);
            af0[j] = (short)u0;
            af1[j] = (short)u1;
            ls0 += bf2f(u0);   // denominator from bf16-rounded p: consistent with MFMA numerator
            ls1 += bf2f(u1);
        }
        #pragma unroll
        for (int nt = 0; nt < 8; ++nt) {
            bf16x8 bfr = *(const bf16x8*)(whp + (size_t)(nt << 4) * Nn + j0);
            acc[0][nt] = __builtin_amdgcn_mfma_f32_16x16x32_bf16(af0, bfr, acc[0][nt], 0, 0, 0);
            acc[1][nt] = __builtin_amdgcn_mfma_f32_16x16x32_bf16(af1, bfr, acc[1][nt], 0, 0, 0);
        }
    }

    // row-sum reduction (over quads and waves)
    if (t < 32) l_red[t] = 0.f;
    __syncthreads();
    atomicAdd(&l_red[n16], ls0);
    atomicAdd(&l_red[16 + n16], ls1);
    // cross-wave acc reduction: waves 0,1 write; waves 2,3 add
    if (w < 2) {
        #pragma unroll
        for (int tt = 0; tt < 2; ++tt)
            #pragma unroll
            for (int nt = 0; nt < 8; ++nt)
                #pragma unroll
                for (int r = 0; r < 4; ++r)
                    accbuf[w][tt * 16 + quad * 4 + r][nt * 16 + n16] = acc[tt][nt][r];
    }
    __syncthreads();
    if (w >= 2) {
        #pragma unroll
        for (int tt = 0; tt < 2; ++tt)
            #pragma unroll
            for (int nt = 0; nt < 8; ++nt)
                #pragma unroll
                for (int r = 0; r < 4; ++r)
                    accbuf[w - 2][tt * 16 + quad * 4 + r][nt * 16 + n16] += acc[tt][nt][r];
    }
    __syncthreads();
    // normalize + ELU + coalesced fp32 store
    float* ob = out + ((size_t)(b * Nn + i0)) * FO;
    #pragma unroll
    for (int r = 0; r < 4; ++r) {
        int flat = (r << 10) + (t << 2);
        int m = flat >> 7;
        int f = flat & 127;
        f32x4 v0 = *(const f32x4*)&accbuf[0][m][f];
        f32x4 v1 = *(const f32x4*)&accbuf[1][m][f];
        float l = l_red[m];
        f32x4 o;
        #pragma unroll
        for (int j = 0; j < 4; ++j) {
            float x = (v0[j] + v1[j]) / l;
            o[j] = x > 0.f ? x : expm1f(x);
        }
        *(f32x4*)&ob[(size_t)m * FO + f] = o;
    }
}

extern "C" void kernel_launch(void* const* d_in, const int* in_sizes, int n_in,
                              void* d_out, int out_size, void* d_ws, size_t ws_size,
                              hipStream_t stream)
{
    const float* h   = (const float*)d_in[0];
    const int*   adj = (const int*)d_in[1];
    const float* W   = (const float*)d_in[2];
    const float* a   = (const float*)d_in[3];
    float* out = (float*)d_out;

    char* ws = (char*)d_ws;
    unsigned short* WhT = (unsigned short*)ws;                 // 8*128*2048*2 = 4 MiB
    float* s_src = (float*)(ws + (4u << 20));                  // 64 KiB
    float* s_dst = (float*)(ws + (4u << 20) + (64u << 10));    // 64 KiB
    float* md    = (float*)(ws + (4u << 20) + (128u << 10));   // 32 B

    hipLaunchKernelGGL(gat_wh,   dim3(512), dim3(256), 0, stream, h, W, a, WhT, s_src, s_dst);
    hipLaunchKernelGGL(gat_max,  dim3(8),   dim3(256), 0, stream, s_dst, md);
    hipLaunchKernelGGL(gat_attn, dim3(512), dim3(256), 0, stream, adj, WhT, s_src, s_dst, md, out);
}

// Round 2
// 275.743 us; speedup vs baseline: 1.0549x; 1.0549x over previous
//
#include <hip/hip_runtime.h>
#include <hip/hip_bf16.h>

#define GAT_ALPHA 0.2f
#define LOG2E 1.4426950408889634f

typedef float f32x4 __attribute__((ext_vector_type(4)));
typedef int   i32x4 __attribute__((ext_vector_type(4)));
typedef short bf16x8 __attribute__((ext_vector_type(8)));

static constexpr int Nn  = 2048;
static constexpr int FIN = 256;
static constexpr int FO  = 128;

static __device__ __forceinline__ unsigned short f2bf(float x) {
    __hip_bfloat16 h = __float2bfloat16(x);
    return __builtin_bit_cast(unsigned short, h);
}
static __device__ __forceinline__ float bf2f(unsigned short u) {
    unsigned int v = ((unsigned int)u) << 16;
    return __builtin_bit_cast(float, v);
}

// ---------------------------------------------------------------------------
// Kernel 0 (prep): wa_src[k] = sum_f W[k][f]*a[f], wa_dst[k] = sum_f W[k][f]*a[128+f]
// (associativity: s = (h@W)@a == h@(W@a), keeps s fp32-exact without fp32 Wh)
// Also inits md_key[8] = 0 (key encoding of -inf) for the atomicMax in gat_wh.
// ---------------------------------------------------------------------------
__global__ __launch_bounds__(256) void gat_prep(
        const float* __restrict__ W, const float* __restrict__ a,
        float* __restrict__ wa, unsigned int* __restrict__ md_key)
{
    __shared__ float pr[32][8];
    __shared__ float pd[32][8];
    const int t = threadIdx.x;
    const int kl = t >> 3, seg = t & 7;
    const int k = blockIdx.x * 32 + kl;
    float ps = 0.f, pv = 0.f;
    const float* wr = W + (size_t)k * FO + seg * 16;
    #pragma unroll
    for (int f = 0; f < 16; f += 4) {
        f32x4 wv = *(const f32x4*)(wr + f);
        f32x4 as = *(const f32x4*)(a + seg * 16 + f);
        f32x4 ad = *(const f32x4*)(a + FO + seg * 16 + f);
        ps += wv[0]*as[0] + wv[1]*as[1] + wv[2]*as[2] + wv[3]*as[3];
        pv += wv[0]*ad[0] + wv[1]*ad[1] + wv[2]*ad[2] + wv[3]*ad[3];
    }
    pr[kl][seg] = ps; pd[kl][seg] = pv;
    __syncthreads();
    if (t < 32) {
        float s = 0.f, d = 0.f;
        #pragma unroll
        for (int j = 0; j < 8; ++j) { s += pr[t][j]; d += pd[t][j]; }
        wa[blockIdx.x * 32 + t]       = s;
        wa[256 + blockIdx.x * 32 + t] = d;
    }
    if (blockIdx.x == 0 && t < 8) md_key[t] = 0u;   // key(-inf)
}

// ---------------------------------------------------------------------------
// Kernel 1: WhT[b][f][n] = bf16(h@W) via MFMA (W staged to LDS bf16, transposed,
// padded stride 264 to break bank aliasing). s_src/s_dst = h@wa in fp32 exact.
// Per-batch max(s_dst) via order-preserving uint atomicMax into md_key[b].
// Block: 64 rows of one batch, 4 waves x (16 rows x 128 feats).
// ---------------------------------------------------------------------------
__global__ __launch_bounds__(256) void gat_wh(
        const float* __restrict__ h, const float* __restrict__ W,
        const float* __restrict__ wa, unsigned short* __restrict__ WhT,
        float* __restrict__ s_src, float* __restrict__ s_dst,
        unsigned int* __restrict__ md_key)
{
    __shared__ unsigned short WT[FO][264];  // 67.6 KB, [f][k] bf16, padded
    __shared__ float wal[512];
    __shared__ float sred[64][4][2];
    __shared__ float red64[64];
    const int t  = threadIdx.x;
    const int b  = blockIdx.x & 7;
    const int n0 = (blockIdx.x >> 3) << 6;

    if (t < 128) *(f32x4*)&wal[t * 4] = *(const f32x4*)&wa[t * 4];
    // stage W -> WT (bf16, transposed)
    #pragma unroll
    for (int c = 0; c < 32; ++c) {
        int flat = c * 1024 + t * 4;
        int k = flat >> 7, f = flat & 127;
        f32x4 wv = *(const f32x4*)&W[flat];
        WT[f + 0][k] = f2bf(wv[0]);
        WT[f + 1][k] = f2bf(wv[1]);
        WT[f + 2][k] = f2bf(wv[2]);
        WT[f + 3][k] = f2bf(wv[3]);
    }
    __syncthreads();

    // fp32-exact s_src/s_dst: 4 threads per row, 64 k's each
    {
        const int row = t >> 2, seg = t & 3;
        const float* hp  = h + ((size_t)(b * Nn + n0 + row)) * FIN + seg * 64;
        const float* was = &wal[seg * 64];
        const float* wad = &wal[256 + seg * 64];
        float ps = 0.f, pv = 0.f;
        #pragma unroll
        for (int j = 0; j < 64; j += 4) {
            f32x4 hv = *(const f32x4*)(hp + j);
            f32x4 sv = *(const f32x4*)(was + j);
            f32x4 dv = *(const f32x4*)(wad + j);
            ps += hv[0]*sv[0] + hv[1]*sv[1] + hv[2]*sv[2] + hv[3]*sv[3];
            pv += hv[0]*dv[0] + hv[1]*dv[1] + hv[2]*dv[2] + hv[3]*dv[3];
        }
        sred[row][seg][0] = ps;
        sred[row][seg][1] = pv;
    }
    __syncthreads();
    if (t < 64) {
        float s = sred[t][0][0] + sred[t][1][0] + sred[t][2][0] + sred[t][3][0];
        float d = sred[t][0][1] + sred[t][1][1] + sred[t][2][1] + sred[t][3][1];
        s_src[b * Nn + n0 + t] = s;
        s_dst[b * Nn + n0 + t] = d;
        red64[t] = d;
    }
    __syncthreads();
    if (t < 16) red64[t] = fmaxf(fmaxf(red64[t], red64[t + 16]),
                                 fmaxf(red64[t + 32], red64[t + 48]));
    __syncthreads();
    if (t == 0) {
        float m = red64[0];
        #pragma unroll
        for (int j = 1; j < 16; ++j) m = fmaxf(m, red64[j]);
        unsigned int bits = __builtin_bit_cast(unsigned int, m);
        unsigned int key  = (bits & 0x80000000u) ? ~bits : (bits | 0x80000000u);
        atomicMax(md_key + b, key);
    }

    // MFMA Wh: wave w owns rows n0 + w*16 .. +16, full 128 feats
    const int w = t >> 6, lane = t & 63, n16 = lane & 15, quad = lane >> 4;
    const float* ha = h + ((size_t)(b * Nn + n0 + w * 16 + n16)) * FIN + quad * 8;
    f32x4 acc[8] = {};
    #pragma unroll
    for (int ks = 0; ks < 8; ++ks) {
        f32x4 h0 = *(const f32x4*)(ha + ks * 32);
        f32x4 h1 = *(const f32x4*)(ha + ks * 32 + 4);
        bf16x8 af;
        af[0] = (short)f2bf(h0[0]); af[1] = (short)f2bf(h0[1]);
        af[2] = (short)f2bf(h0[2]); af[3] = (short)f2bf(h0[3]);
        af[4] = (short)f2bf(h1[0]); af[5] = (short)f2bf(h1[1]);
        af[6] = (short)f2bf(h1[2]); af[7] = (short)f2bf(h1[3]);
        #pragma unroll
        for (int nt = 0; nt < 8; ++nt) {
            bf16x8 bfr = *(const bf16x8*)&WT[nt * 16 + n16][ks * 32 + quad * 8];
            acc[nt] = __builtin_amdgcn_mfma_f32_16x16x32_bf16(af, bfr, acc[nt], 0, 0, 0);
        }
    }
    // C/D: col(lane&15)=f offset, row(quad*4+reg)=i offset; pack 4 rows -> ushort4
    #pragma unroll
    for (int nt = 0; nt < 8; ++nt) {
        ushort4 pk;
        pk.x = f2bf(acc[nt][0]); pk.y = f2bf(acc[nt][1]);
        pk.z = f2bf(acc[nt][2]); pk.w = f2bf(acc[nt][3]);
        *(ushort4*)&WhT[((size_t)(b * FO + nt * 16 + n16)) * Nn + n0 + w * 16 + quad * 4] = pk;
    }
}

// ---------------------------------------------------------------------------
// Kernel 2: attention + aggregate. 1024 blocks (16 i-rows), 4 waves k-split
// (32 j per wave per 128-j step), register double-buffered adj/s_dst loads,
// MFMA P@WhT, cross-wave LDS reduction epilogue.
// ---------------------------------------------------------------------------
__global__ __launch_bounds__(256, 4) void gat_attn(
        const int* __restrict__ adj, const unsigned short* __restrict__ WhT,
        const float* __restrict__ s_src, const float* __restrict__ s_dst,
        const unsigned int* __restrict__ md_key, float* __restrict__ out)
{
    __shared__ float accbuf[2][16][FO];   // 16 KB
    __shared__ float l_red[16];
    const int t = threadIdx.x, w = t >> 6, lane = t & 63;
    const int n16 = lane & 15, quad = lane >> 4;
    const int b  = blockIdx.x & 7;            // batch per XCD: WhT slice L2-local
    const int i0 = (blockIdx.x >> 3) << 4;

    const unsigned int key = md_key[b];
    const unsigned int mb  = (key & 0x80000000u) ? (key ^ 0x80000000u) : ~key;
    const float mdb = __builtin_bit_cast(float, mb);
    const float ss  = s_src[b * Nn + i0 + n16];
    const float tm  = ss + mdb;
    const float mi  = fmaxf(tm, GAT_ALPHA * tm) * LOG2E;  // row upper bound (lrelu monotone)
    const float ssL = ss * LOG2E;

    const int* aptr = adj + ((size_t)(b * Nn + i0 + n16)) * Nn + quad * 8;
    const float* dptr = s_dst + b * Nn + quad * 8;
    const unsigned short* wptr = WhT + ((size_t)(b * FO + n16)) * Nn + quad * 8;

    f32x4 acc[8] = {};
    float ls = 0.f;
    int jc = w * 32;
    i32x4 A0 = *(const i32x4*)(aptr + jc), A1 = *(const i32x4*)(aptr + jc + 4);
    f32x4 D0 = *(const f32x4*)(dptr + jc), D1 = *(const f32x4*)(dptr + jc + 4);

    for (int s = 0; s < 16; ++s) {
        const int jp = (s < 15) ? (jc + 128) : (w * 32);   // always-valid prefetch addr
        i32x4 nA0 = *(const i32x4*)(aptr + jp);
        i32x4 nA1 = *(const i32x4*)(aptr + jp + 4);
        f32x4 nD0 = *(const f32x4*)(dptr + jp);
        f32x4 nD1 = *(const f32x4*)(dptr + jp + 4);

        float dv[8] = {D0[0],D0[1],D0[2],D0[3],D1[0],D1[1],D1[2],D1[3]};
        int   am[8] = {A0[0],A0[1],A0[2],A0[3],A1[0],A1[1],A1[2],A1[3]};
        bf16x8 af;
        #pragma unroll
        for (int j = 0; j < 8; ++j) {
            float u  = __builtin_fmaf(dv[j], LOG2E, ssL);   // log2-domain score
            float lr = fmaxf(u, GAT_ALPHA * u);             // lrelu commutes with *LOG2E
            float e  = __builtin_amdgcn_exp2f(lr - mi);
            e = (am[j] > 0) ? e : 0.f;                      // mask == exp(NEG_INF - m) -> 0
            unsigned short ub = f2bf(e);
            af[j] = (short)ub;
            ls += bf2f(ub);   // denominator consistent with bf16 numerator
        }
        #pragma unroll
        for (int nt = 0; nt < 8; ++nt) {
            bf16x8 bfr = *(const bf16x8*)(wptr + (size_t)(nt * 16) * Nn + jc);
            acc[nt] = __builtin_amdgcn_mfma_f32_16x16x32_bf16(af, bfr, acc[nt], 0, 0, 0);
        }
        jc = jc + 128; A0 = nA0; A1 = nA1; D0 = nD0; D1 = nD1;
    }

    if (t < 16) l_red[t] = 0.f;
    __syncthreads();
    atomicAdd(&l_red[n16], ls);
    if (w < 2) {
        #pragma unroll
        for (int nt = 0; nt < 8; ++nt)
            #pragma unroll
            for (int r = 0; r < 4; ++r)
                accbuf[w][quad * 4 + r][nt * 16 + n16] = acc[nt][r];
    }
    __syncthreads();
    if (w >= 2) {
        #pragma unroll
        for (int nt = 0; nt < 8; ++nt)
            #pragma unroll
            for (int r = 0; r < 4; ++r)
                accbuf[w - 2][quad * 4 + r][nt * 16 + n16] += acc[nt][r];
    }
    __syncthreads();
    float* ob = out + ((size_t)(b * Nn + i0)) * FO;
    #pragma unroll
    for (int r = 0; r < 2; ++r) {
        int flat = (r << 10) + (t << 2);
        int m = flat >> 7;
        int f = flat & 127;
        f32x4 v0 = *(const f32x4*)&accbuf[0][m][f];
        f32x4 v1 = *(const f32x4*)&accbuf[1][m][f];
        float l = l_red[m];
        f32x4 o;
        #pragma unroll
        for (int j = 0; j < 4; ++j) {
            float x = (v0[j] + v1[j]) / l;
            o[j] = x > 0.f ? x : expm1f(x);
        }
        *(f32x4*)&ob[(size_t)m * FO + f] = o;
    }
}

extern "C" void kernel_launch(void* const* d_in, const int* in_sizes, int n_in,
                              void* d_out, int out_size, void* d_ws, size_t ws_size,
                              hipStream_t stream)
{
    const float* h   = (const float*)d_in[0];
    const int*   adj = (const int*)d_in[1];
    const float* W   = (const float*)d_in[2];
    const float* a   = (const float*)d_in[3];
    float* out = (float*)d_out;

    char* ws = (char*)d_ws;
    unsigned short* WhT = (unsigned short*)ws;                    // 4 MiB
    float* s_src        = (float*)(ws + 4194304);                 // 64 KiB
    float* s_dst        = (float*)(ws + 4259840);                 // 64 KiB
    float* wa           = (float*)(ws + 4325376);                 // 2 KiB
    unsigned int* md_key= (unsigned int*)(ws + 4327424);          // 32 B

    hipLaunchKernelGGL(gat_prep, dim3(8),    dim3(256), 0, stream, W, a, wa, md_key);
    hipLaunchKernelGGL(gat_wh,   dim3(256),  dim3(256), 0, stream, h, W, wa, WhT, s_src, s_dst, md_key);
    hipLaunchKernelGGL(gat_attn, dim3(1024), dim3(256), 0, stream, adj, WhT, s_src, s_dst, md_key, out);
}

// Round 3
// 234.503 us; speedup vs baseline: 1.2404x; 1.1759x over previous
//
#include <hip/hip_runtime.h>
#include <hip/hip_bf16.h>

#define GAT_ALPHA 0.2f
#define LOG2E 1.4426950408889634f

typedef float f32x4 __attribute__((ext_vector_type(4)));
typedef int   i32x4 __attribute__((ext_vector_type(4)));
typedef short bf16x8 __attribute__((ext_vector_type(8)));

static constexpr int Nn  = 2048;
static constexpr int FIN = 256;
static constexpr int FO  = 128;

static __device__ __forceinline__ unsigned short f2bf(float x) {
    __hip_bfloat16 h = __float2bfloat16(x);
    return __builtin_bit_cast(unsigned short, h);
}
static __device__ __forceinline__ float bf2f(unsigned short u) {
    unsigned int v = ((unsigned int)u) << 16;
    return __builtin_bit_cast(float, v);
}

// ---------------------------------------------------------------------------
// Kernel 0 (prep): wa = W@a (both halves), fp32-exact score vectors later.
// Inits md_key[8] = 0 (key encoding of -inf).
// ---------------------------------------------------------------------------
__global__ __launch_bounds__(256) void gat_prep(
        const float* __restrict__ W, const float* __restrict__ a,
        float* __restrict__ wa, unsigned int* __restrict__ md_key)
{
    __shared__ float pr[32][8];
    __shared__ float pd[32][8];
    const int t = threadIdx.x;
    const int kl = t >> 3, seg = t & 7;
    const int k = blockIdx.x * 32 + kl;
    float ps = 0.f, pv = 0.f;
    const float* wr = W + (size_t)k * FO + seg * 16;
    #pragma unroll
    for (int f = 0; f < 16; f += 4) {
        f32x4 wv = *(const f32x4*)(wr + f);
        f32x4 as = *(const f32x4*)(a + seg * 16 + f);
        f32x4 ad = *(const f32x4*)(a + FO + seg * 16 + f);
        ps += wv[0]*as[0] + wv[1]*as[1] + wv[2]*as[2] + wv[3]*as[3];
        pv += wv[0]*ad[0] + wv[1]*ad[1] + wv[2]*ad[2] + wv[3]*ad[3];
    }
    pr[kl][seg] = ps; pd[kl][seg] = pv;
    __syncthreads();
    if (t < 32) {
        float s = 0.f, d = 0.f;
        #pragma unroll
        for (int j = 0; j < 8; ++j) { s += pr[t][j]; d += pd[t][j]; }
        wa[blockIdx.x * 32 + t]       = s;
        wa[256 + blockIdx.x * 32 + t] = d;
    }
    if (blockIdx.x == 0 && t < 8) md_key[t] = 0u;   // key(-inf)
}

// ---------------------------------------------------------------------------
// Kernel 1: WhT[b][f][n] = bf16(h@W) via MFMA; s_src/s_dst fp32-exact via wa;
// per-batch max(s_dst) via order-preserving uint atomicMax.
// ---------------------------------------------------------------------------
__global__ __launch_bounds__(256) void gat_wh(
        const float* __restrict__ h, const float* __restrict__ W,
        const float* __restrict__ wa, unsigned short* __restrict__ WhT,
        float* __restrict__ s_src, float* __restrict__ s_dst,
        unsigned int* __restrict__ md_key)
{
    __shared__ unsigned short WT[FO][264];  // [f][k] bf16, padded
    __shared__ float wal[512];
    __shared__ float sred[64][4][2];
    __shared__ float red64[64];
    const int t  = threadIdx.x;
    const int b  = blockIdx.x & 7;
    const int n0 = (blockIdx.x >> 3) << 6;

    if (t < 128) *(f32x4*)&wal[t * 4] = *(const f32x4*)&wa[t * 4];
    #pragma unroll
    for (int c = 0; c < 32; ++c) {
        int flat = c * 1024 + t * 4;
        int k = flat >> 7, f = flat & 127;
        f32x4 wv = *(const f32x4*)&W[flat];
        WT[f + 0][k] = f2bf(wv[0]);
        WT[f + 1][k] = f2bf(wv[1]);
        WT[f + 2][k] = f2bf(wv[2]);
        WT[f + 3][k] = f2bf(wv[3]);
    }
    __syncthreads();

    {
        const int row = t >> 2, seg = t & 3;
        const float* hp  = h + ((size_t)(b * Nn + n0 + row)) * FIN + seg * 64;
        const float* was = &wal[seg * 64];
        const float* wad = &wal[256 + seg * 64];
        float ps = 0.f, pv = 0.f;
        #pragma unroll
        for (int j = 0; j < 64; j += 4) {
            f32x4 hv = *(const f32x4*)(hp + j);
            f32x4 sv = *(const f32x4*)(was + j);
            f32x4 dv = *(const f32x4*)(wad + j);
            ps += hv[0]*sv[0] + hv[1]*sv[1] + hv[2]*sv[2] + hv[3]*sv[3];
            pv += hv[0]*dv[0] + hv[1]*dv[1] + hv[2]*dv[2] + hv[3]*dv[3];
        }
        sred[row][seg][0] = ps;
        sred[row][seg][1] = pv;
    }
    __syncthreads();
    if (t < 64) {
        float s = sred[t][0][0] + sred[t][1][0] + sred[t][2][0] + sred[t][3][0];
        float d = sred[t][0][1] + sred[t][1][1] + sred[t][2][1] + sred[t][3][1];
        s_src[b * Nn + n0 + t] = s;
        s_dst[b * Nn + n0 + t] = d;
        red64[t] = d;
    }
    __syncthreads();
    if (t < 16) red64[t] = fmaxf(fmaxf(red64[t], red64[t + 16]),
                                 fmaxf(red64[t + 32], red64[t + 48]));
    __syncthreads();
    if (t == 0) {
        float m = red64[0];
        #pragma unroll
        for (int j = 1; j < 16; ++j) m = fmaxf(m, red64[j]);
        unsigned int bits = __builtin_bit_cast(unsigned int, m);
        unsigned int key  = (bits & 0x80000000u) ? ~bits : (bits | 0x80000000u);
        atomicMax(md_key + b, key);
    }

    const int w = t >> 6, lane = t & 63, n16 = lane & 15, quad = lane >> 4;
    const float* ha = h + ((size_t)(b * Nn + n0 + w * 16 + n16)) * FIN + quad * 8;
    f32x4 acc[8] = {};
    #pragma unroll
    for (int ks = 0; ks < 8; ++ks) {
        f32x4 h0 = *(const f32x4*)(ha + ks * 32);
        f32x4 h1 = *(const f32x4*)(ha + ks * 32 + 4);
        bf16x8 af;
        af[0] = (short)f2bf(h0[0]); af[1] = (short)f2bf(h0[1]);
        af[2] = (short)f2bf(h0[2]); af[3] = (short)f2bf(h0[3]);
        af[4] = (short)f2bf(h1[0]); af[5] = (short)f2bf(h1[1]);
        af[6] = (short)f2bf(h1[2]); af[7] = (short)f2bf(h1[3]);
        #pragma unroll
        for (int nt = 0; nt < 8; ++nt) {
            bf16x8 bfr = *(const bf16x8*)&WT[nt * 16 + n16][ks * 32 + quad * 8];
            acc[nt] = __builtin_amdgcn_mfma_f32_16x16x32_bf16(af, bfr, acc[nt], 0, 0, 0);
        }
    }
    #pragma unroll
    for (int nt = 0; nt < 8; ++nt) {
        ushort4 pk;
        pk.x = f2bf(acc[nt][0]); pk.y = f2bf(acc[nt][1]);
        pk.z = f2bf(acc[nt][2]); pk.w = f2bf(acc[nt][3]);
        *(ushort4*)&WhT[((size_t)(b * FO + nt * 16 + n16)) * Nn + n0 + w * 16 + quad * 4] = pk;
    }
}

// ---------------------------------------------------------------------------
// Kernel 2 (v3): 512 blocks = 64 i-tiles(32 rows) x 8 batches. 128-j tiles.
// All global loads wave-contiguous; MFMA operands via LDS:
//   - each thread owns ONE adj row (contiguous 128 B runs, 8 segs/inst)
//   - P computed in regs -> bf16 LDS tile (stride 136, A-frag layout)
//   - WhT staged coalesced (16 B/lane, 4x256 B segs) -> LDS (stride 136)
//   - wave w does k-step w (32 j) of each tile: 16 MFMA from ds_read_b128
// Epilogue: accbuf (stride 132) aliases the WhT-tile LDS.
// ---------------------------------------------------------------------------
__global__ __launch_bounds__(256, 3) void gat_attn(
        const int* __restrict__ adj, const unsigned short* __restrict__ WhT,
        const float* __restrict__ s_src, const float* __restrict__ s_dst,
        const unsigned int* __restrict__ md_key, float* __restrict__ out)
{
    constexpr int WS = 136;           // wht tile row stride (bf16 elems)
    constexpr int PS = 136;           // P tile row stride
    constexpr int AS = 132;           // accbuf row stride (f32)
    __shared__ __align__(16) unsigned short whs[128 * WS];   // 34816 B (aliased by accbuf)
    __shared__ __align__(16) unsigned short psT[32 * PS];    // 8704 B
    __shared__ float l_red[32];
    float* accbuf = (float*)whs;      // 2*32*AS*4 = 33792 B <= 34816

    const int t = threadIdx.x, w = t >> 6, lane = t & 63;
    const int n16 = lane & 15, quad = lane >> 4;
    const int b  = blockIdx.x & 7;
    const int i0 = (blockIdx.x >> 3) << 5;
    const int r  = t >> 3;            // this thread's i-row (0..31)
    const int jg = t & 7;             // j subgroup 0..7

    if (t < 32) l_red[t] = 0.f;

    const unsigned int key = md_key[b];
    const unsigned int mb  = (key & 0x80000000u) ? (key ^ 0x80000000u) : ~key;
    const float mdb = __builtin_bit_cast(float, mb);
    const float ssr = s_src[b * Nn + i0 + r];
    const float tm  = ssr + mdb;
    const float mi  = fmaxf(tm, GAT_ALPHA * tm) * LOG2E;  // row upper bound (lrelu monotone)
    const float ssL = ssr * LOG2E;

    const int* arow = adj + ((size_t)(b * Nn + i0 + r)) * Nn;
    const float* dB = s_dst + b * Nn;
    const unsigned short* wrow = WhT + ((size_t)(b * FO + (w << 5))) * Nn;
    const int fsub = lane >> 4;       // 0..3: f-row within 4-row staging group
    const int jc16 = lane & 15;       // 16 B chunk index within 128-j row

    f32x4 acc[2][8] = {};
    float ls = 0.f;

    // prefetch tile 0 adj (per-thread contiguous within its row)
    i32x4 pa[4];
    #pragma unroll
    for (int k = 0; k < 4; ++k) pa[k] = *(const i32x4*)(arow + (jg << 2) + (k << 5));

    for (int s = 0; s < 16; ++s) {
        const int j0 = s << 7;
        // stage WhT tile: wave w covers f-rows [w*32, w*32+32)
        bf16x8 wreg[8];
        #pragma unroll
        for (int i = 0; i < 8; ++i)
            wreg[i] = *(const bf16x8*)(wrow + (size_t)((i << 2) + fsub) * Nn + j0 + (jc16 << 3));
        // compute P for row r, 16 j's (in 4 interleaved groups of 4)
        float e16[16];
        #pragma unroll
        for (int k = 0; k < 4; ++k) {
            f32x4 dv = *(const f32x4*)(dB + j0 + (jg << 2) + (k << 5));
            #pragma unroll
            for (int j = 0; j < 4; ++j) {
                float u  = __builtin_fmaf(dv[j], LOG2E, ssL);
                float lr = fmaxf(u, GAT_ALPHA * u);
                float e  = __builtin_amdgcn_exp2f(lr - mi);
                e16[k * 4 + j] = (pa[k][j] > 0) ? e : 0.f;   // mask == exp(NEG_INF-m)->0
            }
        }
        // prefetch next tile's adj before the barrier
        const int jn = (s < 15) ? (j0 + 128) : 0;
        #pragma unroll
        for (int k = 0; k < 4; ++k) pa[k] = *(const i32x4*)(arow + jn + (jg << 2) + (k << 5));
        // pack bf16, accumulate denominator (consistent with MFMA numerator), write P-tile
        #pragma unroll
        for (int k = 0; k < 4; ++k) {
            unsigned short u0 = f2bf(e16[k*4+0]), u1 = f2bf(e16[k*4+1]);
            unsigned short u2 = f2bf(e16[k*4+2]), u3 = f2bf(e16[k*4+3]);
            ls += bf2f(u0) + bf2f(u1) + bf2f(u2) + bf2f(u3);
            ushort4 pk; pk.x = u0; pk.y = u1; pk.z = u2; pk.w = u3;
            *(ushort4*)&psT[r * PS + (jg << 2) + (k << 5)] = pk;
        }
        // write wht tile
        #pragma unroll
        for (int i = 0; i < 8; ++i)
            *(bf16x8*)&whs[((w << 5) + (i << 2) + fsub) * WS + (jc16 << 3)] = wreg[i];
        __syncthreads();
        // MFMA: wave w handles j-window [w*32, w*32+32) of this tile
        bf16x8 bfr[8];
        #pragma unroll
        for (int nt = 0; nt < 8; ++nt)
            bfr[nt] = *(const bf16x8*)&whs[((nt << 4) + n16) * WS + (w << 5) + (quad << 3)];
        #pragma unroll
        for (int ig = 0; ig < 2; ++ig) {
            bf16x8 af = *(const bf16x8*)&psT[((ig << 4) + n16) * PS + (w << 5) + (quad << 3)];
            #pragma unroll
            for (int nt = 0; nt < 8; ++nt)
                acc[ig][nt] = __builtin_amdgcn_mfma_f32_16x16x32_bf16(af, bfr[nt], acc[ig][nt], 0, 0, 0);
        }
        __syncthreads();
    }

    // denominator reduction
    atomicAdd(&l_red[r], ls);
    // cross-wave accumulator reduction (accbuf aliases whs; last barrier passed)
    if (w < 2) {
        #pragma unroll
        for (int ig = 0; ig < 2; ++ig)
            #pragma unroll
            for (int nt = 0; nt < 8; ++nt)
                #pragma unroll
                for (int rr = 0; rr < 4; ++rr)
                    accbuf[(size_t)w * 32 * AS + (ig * 16 + quad * 4 + rr) * AS + nt * 16 + n16] = acc[ig][nt][rr];
    }
    __syncthreads();
    if (w >= 2) {
        #pragma unroll
        for (int ig = 0; ig < 2; ++ig)
            #pragma unroll
            for (int nt = 0; nt < 8; ++nt)
                #pragma unroll
                for (int rr = 0; rr < 4; ++rr)
                    accbuf[(size_t)(w - 2) * 32 * AS + (ig * 16 + quad * 4 + rr) * AS + nt * 16 + n16] += acc[ig][nt][rr];
    }
    __syncthreads();
    // normalize + ELU + coalesced store
    float* ob = out + ((size_t)(b * Nn + i0)) * FO;
    #pragma unroll
    for (int c = 0; c < 4; ++c) {
        int flat = c * 1024 + t * 4;
        int m = flat >> 7, f = flat & 127;
        f32x4 v0 = *(const f32x4*)&accbuf[(size_t)m * AS + f];
        f32x4 v1 = *(const f32x4*)&accbuf[(size_t)32 * AS + m * AS + f];
        float l = l_red[m];
        f32x4 o;
        #pragma unroll
        for (int j = 0; j < 4; ++j) {
            float x = (v0[j] + v1[j]) / l;
            o[j] = x > 0.f ? x : expm1f(x);
        }
        *(f32x4*)&ob[(size_t)m * FO + f] = o;
    }
}

extern "C" void kernel_launch(void* const* d_in, const int* in_sizes, int n_in,
                              void* d_out, int out_size, void* d_ws, size_t ws_size,
                              hipStream_t stream)
{
    const float* h   = (const float*)d_in[0];
    const int*   adj = (const int*)d_in[1];
    const float* W   = (const float*)d_in[2];
    const float* a   = (const float*)d_in[3];
    float* out = (float*)d_out;

    char* ws = (char*)d_ws;
    unsigned short* WhT = (unsigned short*)ws;                    // 4 MiB
    float* s_src        = (float*)(ws + 4194304);                 // 8 KiB
    float* s_dst        = (float*)(ws + 4259840);                 // 8 KiB
    float* wa           = (float*)(ws + 4325376);                 // 2 KiB
    unsigned int* md_key= (unsigned int*)(ws + 4327424);          // 32 B

    hipLaunchKernelGGL(gat_prep, dim3(8),   dim3(256), 0, stream, W, a, wa, md_key);
    hipLaunchKernelGGL(gat_wh,   dim3(256), dim3(256), 0, stream, h, W, wa, WhT, s_src, s_dst, md_key);
    hipLaunchKernelGGL(gat_attn, dim3(512), dim3(256), 0, stream, adj, WhT, s_src, s_dst, md_key, out);
}